// Round 9
// baseline (303.021 us; speedup 1.0000x reference)
//
#include <hip/hip_runtime.h>

// Problem constants (B=8, T=4096, C=512)
#define BB 8
#define TT 4096
#define CC 512
#define MM (BB * TT)   // 32768 rows
#define SS 128         // scan chunks
#define LL 32          // steps per chunk (SS*LL == TT)

typedef short short8 __attribute__((ext_vector_type(8)));
typedef unsigned short ushort8 __attribute__((ext_vector_type(8)));
typedef float f32x4 __attribute__((ext_vector_type(4)));

__device__ __forceinline__ unsigned short f2bf(float f) {
    unsigned int u = __float_as_uint(f);
    u += 0x7FFFu + ((u >> 16) & 1u);   // RNE
    return (unsigned short)(u >> 16);
}
__device__ __forceinline__ float bf2f(unsigned short h) {
    return __uint_as_float(((unsigned int)h) << 16);
}

// async global->LDS, 16B per lane. LDS dest must be wave-uniform base + lane*16.
__device__ __forceinline__ void gl_lds16(const void* g, void* l) {
    __builtin_amdgcn_global_load_lds(
        (__attribute__((address_space(1))) void*)(unsigned long long)g,
        (__attribute__((address_space(3))) void*)(unsigned int)(unsigned long long)l,
        16, 0, 0);
}

__device__ __forceinline__ ushort8 pack8(f32x4 a, f32x4 b) {
    ushort8 r;
    r[0] = f2bf(a.x); r[1] = f2bf(a.y); r[2] = f2bf(a.z); r[3] = f2bf(a.w);
    r[4] = f2bf(b.x); r[5] = f2bf(b.y); r[6] = f2bf(b.z); r[7] = f2bf(b.w);
    return r;
}

// ---------------------------------------------------------------------------
// Kernel 1: prep = weight transpose (blocks 0..255) + time-shift mix
// (blocks 256..8447) fused into one dispatch.
// ---------------------------------------------------------------------------
__global__ __launch_bounds__(256) void prep(
    const float* __restrict__ x,
    const float* __restrict__ mixk, const float* __restrict__ mixv,
    const float* __restrict__ mixr,
    const float* __restrict__ wk, const float* __restrict__ wv,
    const float* __restrict__ wr, const float* __restrict__ wo,
    unsigned short* __restrict__ wT,
    unsigned short* __restrict__ kx, unsigned short* __restrict__ vx,
    unsigned short* __restrict__ rx) {
    __shared__ float t[64][65];
    if (blockIdx.x < 256) {
        const int bid = blockIdx.x;
        const int which = bid >> 6;
        const int rem = bid & 63;
        const int k0 = (rem >> 3) * 64;
        const int n0 = (rem & 7) * 64;
        const float* src = (which == 0) ? wk : (which == 1) ? wv
                         : (which == 2) ? wr : wo;
        const int r = threadIdx.x >> 6;
        const int c = threadIdx.x & 63;
#pragma unroll
        for (int p = 0; p < 16; ++p)
            t[p * 4 + r][c] = src[(size_t)(k0 + p * 4 + r) * CC + n0 + c];
        __syncthreads();
        unsigned short* dst = wT + (size_t)which * (CC * CC);
#pragma unroll
        for (int p = 0; p < 16; ++p)
            dst[(size_t)(n0 + p * 4 + r) * CC + k0 + c] = f2bf(t[c][p * 4 + r]);
        return;
    }
    const int idx = (blockIdx.x - 256) * 256 + threadIdx.x;
    const int row = idx >> 6;
    const int ch  = (idx & 63) * 8;
    const int tt  = row & (TT - 1);
    const size_t off = (size_t)row * CC + ch;
    const float* xr = x + off;

    const f32x4 zero4 = {0.f, 0.f, 0.f, 0.f};
    const f32x4 one4  = {1.f, 1.f, 1.f, 1.f};

    f32x4 xc0 = ((const f32x4*)xr)[0];
    f32x4 xc1 = ((const f32x4*)xr)[1];
    f32x4 xp0 = zero4, xp1 = zero4;
    if (tt != 0) {
        xp0 = ((const f32x4*)(xr - CC))[0];
        xp1 = ((const f32x4*)(xr - CC))[1];
    }

    f32x4 m0, m1;
    m0 = ((const f32x4*)(mixk + ch))[0];
    m1 = ((const f32x4*)(mixk + ch))[1];
    *(ushort8*)(kx + off) = pack8(xc0 * m0 + xp0 * (one4 - m0),
                                  xc1 * m1 + xp1 * (one4 - m1));
    m0 = ((const f32x4*)(mixv + ch))[0];
    m1 = ((const f32x4*)(mixv + ch))[1];
    *(ushort8*)(vx + off) = pack8(xc0 * m0 + xp0 * (one4 - m0),
                                  xc1 * m1 + xp1 * (one4 - m1));
    m0 = ((const f32x4*)(mixr + ch))[0];
    m1 = ((const f32x4*)(mixr + ch))[1];
    *(ushort8*)(rx + off) = pack8(xc0 * m0 + xp0 * (one4 - m0),
                                  xc1 * m1 + xp1 * (one4 - m1));
}

// ---------------------------------------------------------------------------
// GEMM body: 128x128 tile (m112: best tile at this structure), 3-deep LDS
// pipeline, counted vmcnt, raw barriers, 3 blocks/CU (48 KiB LDS).
// Per K-step kt: STG(kt+2) | vmcnt(8) | barrier-A | ds_read+MFMA (compiler
// lgkm-counted interleave) | lgkmcnt(0) | barrier-B.
// vmcnt(8) = 2 stages x 4 loads in flight => own stage(kt) landed.
// Swizzle identical to the measured-0-conflict one: store group g of row r
// at g ^ ((r>>1)&3); read with q ^ ((l16>>1)&3). Row+64 preserves (r>>1)&3.
// ---------------------------------------------------------------------------
template <bool F32OUT>
__device__ __forceinline__ void gemm_body(
    const unsigned short* __restrict__ A,
    const unsigned short* __restrict__ Bw,
    void* __restrict__ OutP, const int sig,
    const int pm, const int pn) {
    __shared__ unsigned short As[3][128 * 32];    // 3 x 8 KiB
    __shared__ unsigned short Bs[3][128 * 32];    // 3 x 8 KiB (48 KiB total)

    const int tid = threadIdx.x;
    const int ar = tid >> 2;                        // 0..63
    const int cg = (tid & 3) ^ ((tid >> 3) & 3);
    const unsigned short* agA = A  + (size_t)(pm * 128 + ar) * CC + cg * 8;
    const unsigned short* agB = Bw + (size_t)(pn * 128 + ar) * CC + cg * 8;

    const int w = tid >> 6, lane = tid & 63;
    const int wr = w >> 1, wc = w & 1;              // 2x2 wave grid
    const int q = lane >> 4, l16 = lane & 15;
    const int sw = (q ^ ((l16 >> 1) & 3)) * 8;      // reader-side swizzle

    f32x4 acc[4][4];
#pragma unroll
    for (int i = 0; i < 4; i++)
#pragma unroll
        for (int j = 0; j < 4; j++) acc[i][j] = (f32x4){0.f, 0.f, 0.f, 0.f};

#define STG(bi, k0) do {                                                        \
    gl_lds16(agA + (k0), &As[bi][tid * 8]);                                     \
    gl_lds16(agA + (size_t)64 * CC + (k0), &As[bi][(256 + tid) * 8]);           \
    gl_lds16(agB + (k0), &Bs[bi][tid * 8]);                                     \
    gl_lds16(agB + (size_t)64 * CC + (k0), &Bs[bi][(256 + tid) * 8]);           \
} while (0)

    STG(0, 0);
    STG(1, 32);

#pragma unroll
    for (int kt = 0; kt < 16; ++kt) {
        const int bi = kt % 3;                      // compile-time (unrolled)
        if (kt + 2 < 16) STG((kt + 2) % 3, (kt + 2) * 32);

        if (kt < 14)       asm volatile("s_waitcnt vmcnt(8)" ::: "memory");
        else if (kt == 14) asm volatile("s_waitcnt vmcnt(4)" ::: "memory");
        else               asm volatile("s_waitcnt vmcnt(0)" ::: "memory");
        __builtin_amdgcn_s_barrier();               // buf[bi] ready for all

        __builtin_amdgcn_s_setprio(1);
        short8 a[4], b[4];
#pragma unroll
        for (int i = 0; i < 4; i++)
            a[i] = *(const short8*)&As[bi][(wr * 64 + i * 16 + l16) * 32 + sw];
#pragma unroll
        for (int j = 0; j < 4; j++)
            b[j] = *(const short8*)&Bs[bi][(wc * 64 + j * 16 + l16) * 32 + sw];
#pragma unroll
        for (int i = 0; i < 4; i++)
#pragma unroll
            for (int j = 0; j < 4; j++)
                acc[i][j] = __builtin_amdgcn_mfma_f32_16x16x32_bf16(a[i], b[j], acc[i][j], 0, 0, 0);
        __builtin_amdgcn_s_setprio(0);

        asm volatile("s_waitcnt lgkmcnt(0)" ::: "memory");  // reads retired
        __builtin_amdgcn_s_barrier();               // WAR: safe to overwrite
    }
#undef STG

    // epilogue: row = wr*64 + i*16 + q*4 + ii, col = pn*128 + wc*64 + j*16 + l16
    const size_t rb = (size_t)pm * 128 + wr * 64;
    const int nb = pn * 128 + wc * 64;
    if constexpr (F32OUT) {
        float* Out = (float*)OutP;
#pragma unroll
        for (int i = 0; i < 4; i++)
#pragma unroll
            for (int j = 0; j < 4; j++)
#pragma unroll
                for (int ii = 0; ii < 4; ii++) {
                    const int m = i * 16 + q * 4 + ii;
                    const int n = nb + j * 16 + l16;
                    Out[(rb + m) * CC + n] = acc[i][j][ii];
                }
    } else {
        unsigned short* Out = (unsigned short*)OutP;
#pragma unroll
        for (int i = 0; i < 4; i++)
#pragma unroll
            for (int j = 0; j < 4; j++)
#pragma unroll
                for (int ii = 0; ii < 4; ii++) {
                    const int m = i * 16 + q * 4 + ii;
                    const int n = nb + j * 16 + l16;
                    float val = acc[i][j][ii];
                    if (sig) val = 1.0f / (1.0f + __expf(-val));
                    Out[(rb + m) * CC + n] = f2bf(val);
                }
    }
}

// ---------------------------------------------------------------------------
// Kernel 2: all three branch GEMMs in ONE dispatch. 1024 blocks/branch
// (256 pm x 4 pn), 3 blocks/CU. XCD swizzle: 4 consecutive wg share pm
// (A-panel L2 reuse within an XCD); 1024 % 8 == 0, bijective.
// ---------------------------------------------------------------------------
__global__ __launch_bounds__(256, 3) void gemm_kvr3(
    const unsigned short* __restrict__ wT,
    const unsigned short* __restrict__ A0, const unsigned short* __restrict__ A1,
    const unsigned short* __restrict__ A2,
    unsigned short* __restrict__ O0, unsigned short* __restrict__ O1,
    unsigned short* __restrict__ O2) {
    const int z = blockIdx.y;
    const int lin = blockIdx.x;                    // 0..1023
    const int wg = (lin & 7) * 128 + (lin >> 3);   // XCD-contiguous
    const int pm = wg >> 2, pn = wg & 3;
    const unsigned short* A = (z == 0) ? A0 : (z == 1) ? A1 : A2;
    unsigned short* O = (z == 0) ? O0 : (z == 1) ? O1 : O2;
    gemm_body<false>(A, wT + (size_t)z * (CC * CC), O, z == 2, pm, pn);
}

// ---------------------------------------------------------------------------
// Kernel 3: out = z @ wo (fp32 output), same body. 1024 blocks.
// ---------------------------------------------------------------------------
__global__ __launch_bounds__(256, 3) void gemm_out(
    const unsigned short* __restrict__ zb, const unsigned short* __restrict__ woT,
    float* __restrict__ out) {
    const int lin = blockIdx.x;
    const int wg = (lin & 7) * 128 + (lin >> 3);
    gemm_body<true>(zb, woT, out, 0, wg >> 2, wg & 3);
}

// ---------------------------------------------------------------------------
// WKV chunked parallel scan (unchanged, verified).
// ---------------------------------------------------------------------------
__global__ __launch_bounds__(256) void wkv_part1(
    const unsigned short* __restrict__ kb, const unsigned short* __restrict__ vb,
    const float* __restrict__ sd,
    float* __restrict__ sp_, float* __restrict__ sq_, float* __restrict__ so_) {
    const int idx = blockIdx.x * 256 + threadIdx.x;
    const int c = idx & (CC - 1);
    const int b = (idx >> 9) & (BB - 1);
    const int s = idx >> 12;
    const float w = sd[c] * (1.0f / (float)TT);
    const size_t base = ((size_t)b * TT + (size_t)s * LL) * CC + c;
    const unsigned short* kp = kb + base;
    const unsigned short* vp = vb + base;

    float p = 0.f, q = 0.f, o = -1e38f;
#pragma unroll 8
    for (int i = 0; i < LL; ++i) {
        const float kt = bf2f(kp[(size_t)i * CC]);
        const float vt = bf2f(vp[(size_t)i * CC]);
        const float no2 = fmaxf(w + o, kt);
        const float A2  = __expf(w + o - no2);
        const float B2  = __expf(kt - no2);
        p = A2 * p + B2 * vt;
        q = A2 * q + B2;
        o = no2;
    }
    sp_[idx] = p; sq_[idx] = q; so_[idx] = o;
}

__global__ __launch_bounds__(256) void wkv_scan(
    const float* __restrict__ sd,
    float* __restrict__ sp_, float* __restrict__ sq_, float* __restrict__ so_) {
    __shared__ float P[2][128], Q[2][128], O[2][128];
    const int gsub = threadIdx.x >> 7;
    const int s    = threadIdx.x & 127;
    const int g    = blockIdx.x * 2 + gsub;
    const int c    = g & (CC - 1);
    const float wL = sd[c] * ((float)LL / (float)TT);
    const int stride = BB * CC;

    float p = sp_[s * stride + g];
    float q = sq_[s * stride + g];
    float o = so_[s * stride + g];
    P[gsub][s] = p; Q[gsub][s] = q; O[gsub][s] = o;

    float dec = wL;
#pragma unroll
    for (int d = 0; d < 7; ++d) {
        const int off = 1 << d;
        __syncthreads();
        float pl = 0.f, ql = 0.f, ol = -1e38f;
        if (s >= off) {
            pl = P[gsub][s - off]; ql = Q[gsub][s - off]; ol = O[gsub][s - off];
        }
        __syncthreads();
        if (s >= off) {
            const float no = fmaxf(ol + dec, o);
            const float Al = __expf(ol + dec - no);
            const float Bc = __expf(o - no);
            p = Al * pl + Bc * p;
            q = Al * ql + Bc * q;
            o = no;
            P[gsub][s] = p; Q[gsub][s] = q; O[gsub][s] = o;
        }
        dec += dec;
    }
    __syncthreads();
    float ep = 0.f, eq = 0.f, eo = -1e38f;
    if (s > 0) { ep = P[gsub][s - 1]; eq = Q[gsub][s - 1]; eo = O[gsub][s - 1]; }
    sp_[s * stride + g] = ep;
    sq_[s * stride + g] = eq;
    so_[s * stride + g] = eo;
}

__global__ __launch_bounds__(256) void wkv_part3(
    const unsigned short* __restrict__ kb, const unsigned short* __restrict__ vb,
    const unsigned short* __restrict__ srb,
    const float* __restrict__ sd, const float* __restrict__ sf,
    const float* __restrict__ sp_, const float* __restrict__ sq_,
    const float* __restrict__ so_,
    unsigned short* __restrict__ zb) {
    const int idx = blockIdx.x * 256 + threadIdx.x;
    const int c = idx & (CC - 1);
    const int b = (idx >> 9) & (BB - 1);
    const int s = idx >> 12;
    const float w = sd[c] * (1.0f / (float)TT);
    const float u = sf[c] * (1.0f / (float)TT);
    const size_t base = ((size_t)b * TT + (size_t)s * LL) * CC + c;
    const unsigned short* kp = kb + base;
    const unsigned short* vp = vb + base;
    const unsigned short* sp = srb + base;
    unsigned short* zp = zb + base;

    float p = sp_[idx], q = sq_[idx], o = so_[idx];
#pragma unroll 4
    for (int i = 0; i < LL; ++i) {
        const float kt = bf2f(kp[(size_t)i * CC]);
        const float vt = bf2f(vp[(size_t)i * CC]);
        const float sr = bf2f(sp[(size_t)i * CC]);

        const float no = fmaxf(o, u + kt);
        const float A  = __expf(o - no);
        const float Bt = __expf(u + kt - no);
        const float y  = (A * p + Bt * vt) / (A * q + Bt);
        zp[(size_t)i * CC] = f2bf(sr * y);

        const float no2 = fmaxf(w + o, kt);
        const float A2  = __expf(w + o - no2);
        const float B2  = __expf(kt - no2);
        p = A2 * p + B2 * vt;
        q = A2 * q + B2;
        o = no2;
    }
}

// ---------------------------------------------------------------------------
extern "C" void kernel_launch(void* const* d_in, const int* in_sizes, int n_in,
                              void* d_out, int out_size, void* d_ws, size_t ws_size,
                              hipStream_t stream) {
    const float* x  = (const float*)d_in[0];
    const float* sd = (const float*)d_in[1];
    const float* sf = (const float*)d_in[2];
    const float* mk = (const float*)d_in[3];
    const float* mv = (const float*)d_in[4];
    const float* mr = (const float*)d_in[5];
    const float* wk = (const float*)d_in[6];
    const float* wv = (const float*)d_in[7];
    const float* wr = (const float*)d_in[8];
    const float* wo = (const float*)d_in[9];
    float* out = (float*)d_out;

    // ws layout (168 MiB): wT 2 MiB, b1..b5 5x32 MiB, sp/sq/so 3x2 MiB.
    // Flow:
    //   prep: x -> b1 (xk), b2 (xv), b3 (xr); weights -> wT
    //   gemm: b1@wk -> b4 (k) ; b2@wv -> b5 (v) ; b3@wr -> srS=d_out (sr)
    //   wkv:  (b4, b5, srS) -> b1 (z)
    //   out:  b1 @ wo -> out (fp32, overwrites srS region)
    char* ws = (char*)d_ws;
    unsigned short* wT = (unsigned short*)ws;
    unsigned short* b1 = wT + (size_t)4 * CC * CC;
    unsigned short* b2 = b1 + (size_t)MM * CC;
    unsigned short* b3 = b2 + (size_t)MM * CC;
    unsigned short* b4 = b3 + (size_t)MM * CC;
    unsigned short* b5 = b4 + (size_t)MM * CC;
    float* sp_ = (float*)(b5 + (size_t)MM * CC);
    float* sq_ = sp_ + (size_t)SS * BB * CC;
    float* so_ = sq_ + (size_t)SS * BB * CC;
    unsigned short* woT = wT + (size_t)3 * CC * CC;
    unsigned short* srS = (unsigned short*)d_out;   // bf16 scratch inside out

    prep<<<dim3(256 + (MM * CC / 8) / 256), 256, 0, stream>>>(
        x, mk, mv, mr, wk, wv, wr, wo, wT, b1, b2, b3);

    gemm_kvr3<<<dim3(1024, 3), 256, 0, stream>>>(wT, b1, b2, b3, b4, b5, srS);

    wkv_part1<<<dim3((SS * BB * CC) / 256), 256, 0, stream>>>(b4, b5, sd, sp_, sq_, so_);
    wkv_scan<<<dim3((BB * CC) / 2), 256, 0, stream>>>(sd, sp_, sq_, so_);
    wkv_part3<<<dim3((SS * BB * CC) / 256), 256, 0, stream>>>(
        b4, b5, srS, sd, sf, sp_, sq_, so_, b1);

    gemm_out<<<dim3(1024), 256, 0, stream>>>(b1, woT, out);
}

// Round 10
// 299.302 us; speedup vs baseline: 1.0124x; 1.0124x over previous
//
#include <hip/hip_runtime.h>

// Problem constants (B=8, T=4096, C=512)
#define BB 8
#define TT 4096
#define CC 512
#define MM (BB * TT)   // 32768 rows
#define SS 128         // scan chunks
#define LL 32          // steps per chunk (SS*LL == TT)

typedef short short8 __attribute__((ext_vector_type(8)));
typedef unsigned short ushort8 __attribute__((ext_vector_type(8)));
typedef float f32x4 __attribute__((ext_vector_type(4)));

__device__ __forceinline__ unsigned short f2bf(float f) {
    unsigned int u = __float_as_uint(f);
    u += 0x7FFFu + ((u >> 16) & 1u);   // RNE
    return (unsigned short)(u >> 16);
}
__device__ __forceinline__ float bf2f(unsigned short h) {
    return __uint_as_float(((unsigned int)h) << 16);
}

// async global->LDS, 16B per lane. LDS dest must be wave-uniform base + lane*16.
__device__ __forceinline__ void gl_lds16(const void* g, void* l) {
    __builtin_amdgcn_global_load_lds(
        (__attribute__((address_space(1))) void*)(unsigned long long)g,
        (__attribute__((address_space(3))) void*)(unsigned int)(unsigned long long)l,
        16, 0, 0);
}

__device__ __forceinline__ ushort8 pack8(f32x4 a, f32x4 b) {
    ushort8 r;
    r[0] = f2bf(a.x); r[1] = f2bf(a.y); r[2] = f2bf(a.z); r[3] = f2bf(a.w);
    r[4] = f2bf(b.x); r[5] = f2bf(b.y); r[6] = f2bf(b.z); r[7] = f2bf(b.w);
    return r;
}

// ---------------------------------------------------------------------------
// Kernel 1: prep = weight transpose (blocks 0..255) + time-shift mix
// (blocks 256..8447) fused into one dispatch to cut a launch gap.
// ---------------------------------------------------------------------------
__global__ __launch_bounds__(256) void prep(
    const float* __restrict__ x,
    const float* __restrict__ mixk, const float* __restrict__ mixv,
    const float* __restrict__ mixr,
    const float* __restrict__ wk, const float* __restrict__ wv,
    const float* __restrict__ wr, const float* __restrict__ wo,
    unsigned short* __restrict__ wT,
    unsigned short* __restrict__ kx, unsigned short* __restrict__ vx,
    unsigned short* __restrict__ rx) {
    __shared__ float t[64][65];
    if (blockIdx.x < 256) {
        const int bid = blockIdx.x;
        const int which = bid >> 6;
        const int rem = bid & 63;
        const int k0 = (rem >> 3) * 64;
        const int n0 = (rem & 7) * 64;
        const float* src = (which == 0) ? wk : (which == 1) ? wv
                         : (which == 2) ? wr : wo;
        const int r = threadIdx.x >> 6;
        const int c = threadIdx.x & 63;
#pragma unroll
        for (int p = 0; p < 16; ++p)
            t[p * 4 + r][c] = src[(size_t)(k0 + p * 4 + r) * CC + n0 + c];
        __syncthreads();
        unsigned short* dst = wT + (size_t)which * (CC * CC);
#pragma unroll
        for (int p = 0; p < 16; ++p)
            dst[(size_t)(n0 + p * 4 + r) * CC + k0 + c] = f2bf(t[c][p * 4 + r]);
        return;
    }
    const int idx = (blockIdx.x - 256) * 256 + threadIdx.x;
    const int row = idx >> 6;
    const int ch  = (idx & 63) * 8;
    const int tt  = row & (TT - 1);
    const size_t off = (size_t)row * CC + ch;
    const float* xr = x + off;

    const f32x4 zero4 = {0.f, 0.f, 0.f, 0.f};
    const f32x4 one4  = {1.f, 1.f, 1.f, 1.f};

    f32x4 xc0 = ((const f32x4*)xr)[0];
    f32x4 xc1 = ((const f32x4*)xr)[1];
    f32x4 xp0 = zero4, xp1 = zero4;
    if (tt != 0) {
        xp0 = ((const f32x4*)(xr - CC))[0];
        xp1 = ((const f32x4*)(xr - CC))[1];
    }

    f32x4 m0, m1;
    m0 = ((const f32x4*)(mixk + ch))[0];
    m1 = ((const f32x4*)(mixk + ch))[1];
    *(ushort8*)(kx + off) = pack8(xc0 * m0 + xp0 * (one4 - m0),
                                  xc1 * m1 + xp1 * (one4 - m1));
    m0 = ((const f32x4*)(mixv + ch))[0];
    m1 = ((const f32x4*)(mixv + ch))[1];
    *(ushort8*)(vx + off) = pack8(xc0 * m0 + xp0 * (one4 - m0),
                                  xc1 * m1 + xp1 * (one4 - m1));
    m0 = ((const f32x4*)(mixr + ch))[0];
    m1 = ((const f32x4*)(mixr + ch))[1];
    *(ushort8*)(rx + off) = pack8(xc0 * m0 + xp0 * (one4 - m0),
                                  xc1 * m1 + xp1 * (one4 - m1));
}

// ---------------------------------------------------------------------------
// GEMM body: 128x256 tile, 3-deep LDS pipeline, counted vmcnt, raw barriers.
// Best-measured structure (R2/R6 ~683 TF for 3 fused GEMMs; 0 bank conflicts;
// 2 blocks/CU cross-block MFMA/stage overlap). This is the plain-HIP 2-phase
// structural ceiling at K=512 — verified invariant across 5 structure
// variants (R2/R3/R6/R7/R8/R9).
// Per K-step kt: STG(kt+2) | vmcnt(12) | barrier-A | ds_read+MFMA interleave
//                | lgkmcnt(0) | barrier-B
// LDS swizzle: 16B group g of row r at slot g ^ ((r>>1)&3) -> 2-way max
// (measured 0 bank conflicts).
// ---------------------------------------------------------------------------
template <bool F32OUT>
__device__ __forceinline__ void gemm_body(
    const unsigned short* __restrict__ A,
    const unsigned short* __restrict__ Bw,
    void* __restrict__ OutP, const int sig,
    const int pm, const int pn) {
    __shared__ unsigned short As[3][128 * 32];    // 3 x  8 KiB
    __shared__ unsigned short Bs[3][256 * 32];    // 3 x 16 KiB

    const int tid = threadIdx.x;
    const int ar = tid >> 2;                        // 0..63
    const int cg = (tid & 3) ^ ((tid >> 3) & 3);
    const unsigned short* agA = A  + (size_t)(pm * 128 + ar) * CC + cg * 8;
    const unsigned short* agB = Bw + (size_t)(pn * 256 + ar) * CC + cg * 8;

    const int w = tid >> 6, lane = tid & 63;
    const int wr = w >> 1, wc = w & 1;
    const int q = lane >> 4, l16 = lane & 15;
    const int sw = (q ^ ((l16 >> 1) & 3)) * 8;      // reader-side swizzle

    f32x4 acc[4][8];
#pragma unroll
    for (int i = 0; i < 4; i++)
#pragma unroll
        for (int j = 0; j < 8; j++) acc[i][j] = (f32x4){0.f, 0.f, 0.f, 0.f};

#define STG(bi, k0) do {                                                        \
    gl_lds16(agA + (k0), &As[bi][tid * 8]);                                     \
    gl_lds16(agA + (size_t)64 * CC + (k0), &As[bi][(256 + tid) * 8]);           \
    gl_lds16(agB + (k0),                    &Bs[bi][(0 * 256 + tid) * 8]);      \
    gl_lds16(agB + (size_t)64  * CC + (k0), &Bs[bi][(1 * 256 + tid) * 8]);      \
    gl_lds16(agB + (size_t)128 * CC + (k0), &Bs[bi][(2 * 256 + tid) * 8]);      \
    gl_lds16(agB + (size_t)192 * CC + (k0), &Bs[bi][(3 * 256 + tid) * 8]);      \
} while (0)

    STG(0, 0);
    STG(1, 32);

#pragma unroll
    for (int kt = 0; kt < 16; ++kt) {
        const int bi = kt % 3;                      // compile-time (unrolled)
        if (kt + 2 < 16) STG((kt + 2) % 3, (kt + 2) * 32);

        if (kt < 14)       asm volatile("s_waitcnt vmcnt(12)" ::: "memory");
        else if (kt == 14) asm volatile("s_waitcnt vmcnt(6)" ::: "memory");
        else               asm volatile("s_waitcnt vmcnt(0)" ::: "memory");
        __builtin_amdgcn_s_barrier();               // buf[bi] ready for all

        __builtin_amdgcn_s_setprio(1);
        short8 a[4], b[8];
#pragma unroll
        for (int i = 0; i < 4; i++)
            a[i] = *(const short8*)&As[bi][(wr * 64 + i * 16 + l16) * 32 + sw];
#pragma unroll
        for (int j = 0; j < 8; j++)
            b[j] = *(const short8*)&Bs[bi][(wc * 128 + j * 16 + l16) * 32 + sw];
        // no forced drain here: compiler interleaves MFMAs with counted lgkmcnt
#pragma unroll
        for (int i = 0; i < 4; i++)
#pragma unroll
            for (int j = 0; j < 8; j++)
                acc[i][j] = __builtin_amdgcn_mfma_f32_16x16x32_bf16(a[i], b[j], acc[i][j], 0, 0, 0);
        __builtin_amdgcn_s_setprio(0);

        asm volatile("s_waitcnt lgkmcnt(0)" ::: "memory");  // reads retired
        __builtin_amdgcn_s_barrier();               // WAR: safe to overwrite
    }
#undef STG

    // epilogue: row = wr*64 + i*16 + q*4 + ii, col = pn*256 + wc*128 + j*16 + l16
    const size_t rb = (size_t)pm * 128 + wr * 64;
    const int nb = pn * 256 + wc * 128;
    if constexpr (F32OUT) {
        float* Out = (float*)OutP;
#pragma unroll
        for (int i = 0; i < 4; i++)
#pragma unroll
            for (int j = 0; j < 8; j++)
#pragma unroll
                for (int ii = 0; ii < 4; ii++) {
                    const int m = i * 16 + q * 4 + ii;
                    const int n = nb + j * 16 + l16;
                    Out[(rb + m) * CC + n] = acc[i][j][ii];
                }
    } else {
        unsigned short* Out = (unsigned short*)OutP;
#pragma unroll
        for (int i = 0; i < 4; i++)
#pragma unroll
            for (int j = 0; j < 8; j++)
#pragma unroll
                for (int ii = 0; ii < 4; ii++) {
                    const int m = i * 16 + q * 4 + ii;
                    const int n = nb + j * 16 + l16;
                    float val = acc[i][j][ii];
                    if (sig) val = 1.0f / (1.0f + __expf(-val));
                    Out[(rb + m) * CC + n] = f2bf(val);
                }
    }
}

// ---------------------------------------------------------------------------
// Kernel 2: all three branch GEMMs in ONE dispatch.
// ---------------------------------------------------------------------------
__global__ __launch_bounds__(256, 2) void gemm_kvr3(
    const unsigned short* __restrict__ wT,
    const unsigned short* __restrict__ A0, const unsigned short* __restrict__ A1,
    const unsigned short* __restrict__ A2,
    unsigned short* __restrict__ O0, unsigned short* __restrict__ O1,
    unsigned short* __restrict__ O2) {
    const int z = blockIdx.y;
    const int lin = blockIdx.x;
    const int wg = (lin & 7) * 64 + (lin >> 3);
    const int pm = wg >> 1, pn = wg & 1;
    const unsigned short* A = (z == 0) ? A0 : (z == 1) ? A1 : A2;
    unsigned short* O = (z == 0) ? O0 : (z == 1) ? O1 : O2;
    gemm_body<false>(A, wT + (size_t)z * (CC * CC), O, z == 2, pm, pn);
}

// ---------------------------------------------------------------------------
// Kernel 3: out = z @ wo (fp32 output), same pipeline.
// ---------------------------------------------------------------------------
__global__ __launch_bounds__(256, 2) void gemm_out(
    const unsigned short* __restrict__ zb, const unsigned short* __restrict__ woT,
    float* __restrict__ out) {
    const int lin = blockIdx.x;
    const int wg = (lin & 7) * 64 + (lin >> 3);
    gemm_body<true>(zb, woT, out, 0, wg >> 1, wg & 1);
}

// ---------------------------------------------------------------------------
// WKV chunked parallel scan. part1 (per-chunk local states).
// ---------------------------------------------------------------------------
__global__ __launch_bounds__(256) void wkv_part1(
    const unsigned short* __restrict__ kb, const unsigned short* __restrict__ vb,
    const float* __restrict__ sd,
    float* __restrict__ sp_, float* __restrict__ sq_, float* __restrict__ so_) {
    const int idx = blockIdx.x * 256 + threadIdx.x;
    const int c = idx & (CC - 1);
    const int b = (idx >> 9) & (BB - 1);
    const int s = idx >> 12;
    const float w = sd[c] * (1.0f / (float)TT);
    const size_t base = ((size_t)b * TT + (size_t)s * LL) * CC + c;
    const unsigned short* kp = kb + base;
    const unsigned short* vp = vb + base;

    float p = 0.f, q = 0.f, o = -1e38f;
#pragma unroll 8
    for (int i = 0; i < LL; ++i) {
        const float kt = bf2f(kp[(size_t)i * CC]);
        const float vt = bf2f(vp[(size_t)i * CC]);
        const float no2 = fmaxf(w + o, kt);
        const float A2  = __expf(w + o - no2);
        const float B2  = __expf(kt - no2);
        p = A2 * p + B2 * vt;
        q = A2 * q + B2;
        o = no2;
    }
    sp_[idx] = p; sq_[idx] = q; so_[idx] = o;
}

// ---------------------------------------------------------------------------
// wkv_scan: Hillis-Steele scan over the 128 chunk aggregates, in LDS, per
// (b,c) group. Combine is associative with per-step decay wL*2^d.
// In-place on sp_/sq_/so_; exclusive output (state BEFORE chunk s).
// ---------------------------------------------------------------------------
__global__ __launch_bounds__(256) void wkv_scan(
    const float* __restrict__ sd,
    float* __restrict__ sp_, float* __restrict__ sq_, float* __restrict__ so_) {
    __shared__ float P[2][128], Q[2][128], O[2][128];
    const int gsub = threadIdx.x >> 7;
    const int s    = threadIdx.x & 127;
    const int g    = blockIdx.x * 2 + gsub;
    const int c    = g & (CC - 1);
    const float wL = sd[c] * ((float)LL / (float)TT);
    const int stride = BB * CC;

    float p = sp_[s * stride + g];
    float q = sq_[s * stride + g];
    float o = so_[s * stride + g];
    P[gsub][s] = p; Q[gsub][s] = q; O[gsub][s] = o;

    float dec = wL;
#pragma unroll
    for (int d = 0; d < 7; ++d) {
        const int off = 1 << d;
        __syncthreads();
        float pl = 0.f, ql = 0.f, ol = -1e38f;
        if (s >= off) {
            pl = P[gsub][s - off]; ql = Q[gsub][s - off]; ol = O[gsub][s - off];
        }
        __syncthreads();
        if (s >= off) {
            const float no = fmaxf(ol + dec, o);
            const float Al = __expf(ol + dec - no);
            const float Bc = __expf(o - no);
            p = Al * pl + Bc * p;
            q = Al * ql + Bc * q;
            o = no;
            P[gsub][s] = p; Q[gsub][s] = q; O[gsub][s] = o;
        }
        dec += dec;
    }
    __syncthreads();
    float ep = 0.f, eq = 0.f, eo = -1e38f;
    if (s > 0) { ep = P[gsub][s - 1]; eq = Q[gsub][s - 1]; eo = O[gsub][s - 1]; }
    sp_[s * stride + g] = ep;
    sq_[s * stride + g] = eq;
    so_[s * stride + g] = eo;
}

__global__ __launch_bounds__(256) void wkv_part3(
    const unsigned short* __restrict__ kb, const unsigned short* __restrict__ vb,
    const unsigned short* __restrict__ srb,
    const float* __restrict__ sd, const float* __restrict__ sf,
    const float* __restrict__ sp_, const float* __restrict__ sq_,
    const float* __restrict__ so_,
    unsigned short* __restrict__ zb) {
    const int idx = blockIdx.x * 256 + threadIdx.x;
    const int c = idx & (CC - 1);
    const int b = (idx >> 9) & (BB - 1);
    const int s = idx >> 12;
    const float w = sd[c] * (1.0f / (float)TT);
    const float u = sf[c] * (1.0f / (float)TT);
    const size_t base = ((size_t)b * TT + (size_t)s * LL) * CC + c;
    const unsigned short* kp = kb + base;
    const unsigned short* vp = vb + base;
    const unsigned short* sp = srb + base;
    unsigned short* zp = zb + base;

    float p = sp_[idx], q = sq_[idx], o = so_[idx];
#pragma unroll 4
    for (int i = 0; i < LL; ++i) {
        const float kt = bf2f(kp[(size_t)i * CC]);
        const float vt = bf2f(vp[(size_t)i * CC]);
        const float sr = bf2f(sp[(size_t)i * CC]);

        const float no = fmaxf(o, u + kt);
        const float A  = __expf(o - no);
        const float Bt = __expf(u + kt - no);
        const float y  = (A * p + Bt * vt) / (A * q + Bt);
        zp[(size_t)i * CC] = f2bf(sr * y);

        const float no2 = fmaxf(w + o, kt);
        const float A2  = __expf(w + o - no2);
        const float B2  = __expf(kt - no2);
        p = A2 * p + B2 * vt;
        q = A2 * q + B2;
        o = no2;
    }
}

// ---------------------------------------------------------------------------
extern "C" void kernel_launch(void* const* d_in, const int* in_sizes, int n_in,
                              void* d_out, int out_size, void* d_ws, size_t ws_size,
                              hipStream_t stream) {
    const float* x  = (const float*)d_in[0];
    const float* sd = (const float*)d_in[1];
    const float* sf = (const float*)d_in[2];
    const float* mk = (const float*)d_in[3];
    const float* mv = (const float*)d_in[4];
    const float* mr = (const float*)d_in[5];
    const float* wk = (const float*)d_in[6];
    const float* wv = (const float*)d_in[7];
    const float* wr = (const float*)d_in[8];
    const float* wo = (const float*)d_in[9];
    float* out = (float*)d_out;

    // ws layout (168 MiB): wT 2 MiB, b1..b5 5x32 MiB, sp/sq/so 3x2 MiB.
    // Flow:
    //   prep: x -> b1 (xk), b2 (xv), b3 (xr); weights -> wT
    //   gemm: b1@wk -> b4 (k) ; b2@wv -> b5 (v) ; b3@wr -> srS=d_out (sr)
    //   wkv:  (b4, b5, srS) -> b1 (z)
    //   out:  b1 @ wo -> out (fp32, overwrites srS region)
    char* ws = (char*)d_ws;
    unsigned short* wT = (unsigned short*)ws;
    unsigned short* b1 = wT + (size_t)4 * CC * CC;
    unsigned short* b2 = b1 + (size_t)MM * CC;
    unsigned short* b3 = b2 + (size_t)MM * CC;
    unsigned short* b4 = b3 + (size_t)MM * CC;
    unsigned short* b5 = b4 + (size_t)MM * CC;
    float* sp_ = (float*)(b5 + (size_t)MM * CC);
    float* sq_ = sp_ + (size_t)SS * BB * CC;
    float* so_ = sq_ + (size_t)SS * BB * CC;
    unsigned short* woT = wT + (size_t)3 * CC * CC;
    unsigned short* srS = (unsigned short*)d_out;   // bf16 scratch inside out

    prep<<<dim3(256 + (MM * CC / 8) / 256), 256, 0, stream>>>(
        x, mk, mv, mr, wk, wv, wr, wo, wT, b1, b2, b3);

    gemm_kvr3<<<dim3(512, 3), 256, 0, stream>>>(wT, b1, b2, b3, b4, b5, srS);

    wkv_part1<<<dim3((SS * BB * CC) / 256), 256, 0, stream>>>(b4, b5, sd, sp_, sq_, so_);
    wkv_scan<<<dim3((BB * CC) / 2), 256, 0, stream>>>(sd, sp_, sq_, so_);
    wkv_part3<<<dim3((SS * BB * CC) / 256), 256, 0, stream>>>(
        b4, b5, srS, sd, sf, sp_, sq_, so_, b1);

    gemm_out<<<dim3(512), 256, 0, stream>>>(b1, woT, out);
}